// Round 5
// baseline (324.181 us; speedup 1.0000x reference)
//
#include <hip/hip_runtime.h>

#define NN 50000
#define EE 800000
#define INC 512
#define HIDC 128
#define OUTC 256
#define CAP 64
#define OV_CAP 65536
#define GB1 782               // ceil(NN/64)

typedef __attribute__((ext_vector_type(8))) short bf16x8;
typedef __attribute__((ext_vector_type(4))) float f32x4;

__device__ __forceinline__ short f2bf(float f) {
    unsigned u = __float_as_uint(f);
    unsigned r = u + 0x7fff + ((u >> 16) & 1);   // RNE to bf16
    return (short)(r >> 16);
}
__device__ __forceinline__ float bf2f(short s) {
    return __uint_as_float(((unsigned)(unsigned short)s) << 16);
}

// ---- prep: w1,w2 fp32 -> bf16 (once per call) -----------------------------
__global__ __launch_bounds__(256) void cvt_w(
    const float* __restrict__ w1, const float* __restrict__ w2,
    short* __restrict__ w1b, short* __restrict__ w2b)
{
    int gid = blockIdx.x * 256 + threadIdx.x;    // 24576 float4 slots total
    float4 v;
    short4* dst;
    if (gid < 16384) { v = ((const float4*)w1)[gid]; dst = &((short4*)w1b)[gid]; }
    else             { v = ((const float4*)w2)[gid - 16384]; dst = &((short4*)w2b)[gid - 16384]; }
    short4 s;
    s.x = f2bf(v.x); s.y = f2bf(v.y); s.z = f2bf(v.z); s.w = f2bf(v.w);
    *dst = s;
}

// ---------------------------------------------------------------------------
// Fat kernel: every block first scatters 4 edges/thread into dst-buckets
// (atomic latency hidden behind the gemm's global loads), then computes one
// BM=64 tile of h = bf16(x @ w1^T).  B (w1) is pre-converted bf16.
__global__ __launch_bounds__(256) void fat_build_gemm1(
    const int* __restrict__ ei, int* __restrict__ cnt,
    unsigned short* __restrict__ bucket, int* __restrict__ ovcnt,
    int* __restrict__ ovlist,
    const float* __restrict__ x, const short* __restrict__ w1b,
    short* __restrict__ h)
{
    __shared__ short As[64][72];
    __shared__ short Bs[128][72];

    // ---- build prologue: 4 consecutive edges per thread ----
    {
        long base = ((long)blockIdx.x * 256 + threadIdx.x) * 4;
        if (base < EE) {
            int4 sv = *(const int4*)&ei[base];
            int4 dv = *(const int4*)&ei[EE + base];
            int sp[4] = {sv.x, sv.y, sv.z, sv.w};
            int dp[4] = {dv.x, dv.y, dv.z, dv.w};
            int nk = (EE - base >= 4) ? 4 : (int)(EE - base);
#pragma unroll
            for (int k = 0; k < 4; k++) {
                if (k < nk) {
                    int src = sp[k], dst = dp[k];
                    int pos = atomicAdd(&cnt[dst], 1);
                    if (pos < CAP) bucket[(long)dst * CAP + pos] = (unsigned short)src;
                    else {
                        int o = atomicAdd(ovcnt, 1);
                        if (o < OV_CAP) { ovlist[o * 2] = src; ovlist[o * 2 + 1] = dst; }
                    }
                }
            }
        }
    }

    // ---- gemm1: BM=64, BN=128(all), BK=64; 4 waves, each 32x64 ----
    int tid = threadIdx.x;
    int lane = tid & 63, wave = tid >> 6;
    int row0 = blockIdx.x * 64;
    int wm = (wave & 1) * 32, wn = (wave >> 1) * 64;
    int l16 = lane & 15, quad = lane >> 4;

    f32x4 acc[2][4];
#pragma unroll
    for (int i = 0; i < 2; i++)
#pragma unroll
        for (int j = 0; j < 4; j++) acc[i][j] = {0.f, 0.f, 0.f, 0.f};

    for (int k0 = 0; k0 < INC; k0 += 64) {
        // stage A 64x64 fp32->bf16 (4 float4/thread)
#pragma unroll
        for (int w = 0; w < 4; w++) {
            int f = tid + w * 256;
            int rr = f >> 4, c4 = f & 15;
            int gr = row0 + rr;
            float4 v = make_float4(0.f, 0.f, 0.f, 0.f);
            if (gr < NN) v = *(const float4*)&x[(long)gr * INC + k0 + c4 * 4];
            short4 s;
            s.x = f2bf(v.x); s.y = f2bf(v.y); s.z = f2bf(v.z); s.w = f2bf(v.w);
            *(short4*)&As[rr][c4 * 4] = s;
        }
        // stage B 128x64 bf16 (4 bf16x8/thread)
#pragma unroll
        for (int w = 0; w < 4; w++) {
            int f = tid + w * 256;
            int rr = f >> 3, c8 = f & 7;
            *(bf16x8*)&Bs[rr][c8 * 8] =
                *(const bf16x8*)&w1b[(long)rr * INC + k0 + c8 * 8];
        }
        __syncthreads();

#pragma unroll
        for (int kk = 0; kk < 64; kk += 32) {
            bf16x8 af[2], bfr[4];
#pragma unroll
            for (int i = 0; i < 2; i++)
                af[i] = *(const bf16x8*)&As[wm + i * 16 + l16][kk + quad * 8];
#pragma unroll
            for (int j = 0; j < 4; j++)
                bfr[j] = *(const bf16x8*)&Bs[wn + j * 16 + l16][kk + quad * 8];
#pragma unroll
            for (int i = 0; i < 2; i++)
#pragma unroll
                for (int j = 0; j < 4; j++)
                    acc[i][j] = __builtin_amdgcn_mfma_f32_16x16x32_bf16(
                        af[i], bfr[j], acc[i][j], 0, 0, 0);
        }
        __syncthreads();
    }

#pragma unroll
    for (int i = 0; i < 2; i++)
#pragma unroll
        for (int rr = 0; rr < 4; rr++) {
            int grow = row0 + wm + i * 16 + quad * 4 + rr;
            if (grow < NN)
#pragma unroll
                for (int j = 0; j < 4; j++)
                    h[(long)grow * HIDC + wn + j * 16 + l16] = f2bf(acc[i][j][rr]);
        }
}

// ---------------------------------------------------------------------------
// gather1: r[n] = bf16(relu(sum_{e->n} h[src_e] + b1)).  16 lanes/node.
__global__ __launch_bounds__(256) void gather1_k(
    const short* __restrict__ h, const unsigned short* __restrict__ bucket,
    const int* __restrict__ cnt, const float* __restrict__ b1,
    short* __restrict__ r)
{
    int t = threadIdx.x;
    int node = blockIdx.x * 16 + (t >> 4);
    int c8 = t & 15;
    if (node >= NN) return;
    int m = cnt[node]; if (m > CAP) m = CAP;
    const unsigned short* bk = bucket + (long)node * CAP;
    float acc[8];
#pragma unroll
    for (int k = 0; k < 8; k++) acc[k] = 0.f;
    int j = 0;
    for (; j + 4 <= m; j += 4) {
        ushort4 ss = *(const ushort4*)&bk[j];
        bf16x8 v0 = *(const bf16x8*)&h[((long)ss.x << 7) + c8 * 8];
        bf16x8 v1 = *(const bf16x8*)&h[((long)ss.y << 7) + c8 * 8];
        bf16x8 v2 = *(const bf16x8*)&h[((long)ss.z << 7) + c8 * 8];
        bf16x8 v3 = *(const bf16x8*)&h[((long)ss.w << 7) + c8 * 8];
#pragma unroll
        for (int k = 0; k < 8; k++)
            acc[k] += bf2f(v0[k]) + bf2f(v1[k]) + bf2f(v2[k]) + bf2f(v3[k]);
    }
    for (; j < m; j++) {
        bf16x8 v0 = *(const bf16x8*)&h[((long)bk[j] << 7) + c8 * 8];
#pragma unroll
        for (int k = 0; k < 8; k++) acc[k] += bf2f(v0[k]);
    }
    bf16x8 o;
#pragma unroll
    for (int k = 0; k < 8; k++)
        o[k] = f2bf(fmaxf(acc[k] + b1[c8 * 8 + k], 0.f));
    *(bf16x8*)&r[((long)node << 7) + c8 * 8] = o;
}

// ---------------------------------------------------------------------------
// Fused gather2 + gemm2: block gathers 64 node-rows of r (fp32 acc, rounded
// to bf16 straight into LDS As), then out[64x256] = As @ w2b^T + b2.
__global__ __launch_bounds__(256) void gg2_k(
    const short* __restrict__ r, const unsigned short* __restrict__ bucket,
    const int* __restrict__ cnt, const short* __restrict__ w2b,
    const float* __restrict__ b2, float* __restrict__ out)
{
    __shared__ short As[64][136];   // full K=128 + pad
    __shared__ short Bs[256][72];   // BN=256, BK=64 slab (restaged)

    int tid = threadIdx.x;
    int node0 = blockIdx.x * 64;

    // ---- gather phase: 4 lanes/node, 32 ch/lane ----
    {
        int node = node0 + (tid >> 2);
        int ln = tid & 3;                       // ch block [ln*32, ln*32+32)
        float acc[32];
#pragma unroll
        for (int k = 0; k < 32; k++) acc[k] = 0.f;
        if (node < NN) {
            int m = cnt[node]; if (m > CAP) m = CAP;
            const unsigned short* bk = bucket + (long)node * CAP;
            int j = 0;
            for (; j + 2 <= m; j += 2) {
                int s0 = bk[j], s1 = bk[j + 1];
                const short* p0 = &r[((long)s0 << 7) + ln * 32];
                const short* p1 = &r[((long)s1 << 7) + ln * 32];
                bf16x8 a0 = *(const bf16x8*)(p0);
                bf16x8 a1 = *(const bf16x8*)(p0 + 8);
                bf16x8 a2 = *(const bf16x8*)(p0 + 16);
                bf16x8 a3 = *(const bf16x8*)(p0 + 24);
                bf16x8 c0 = *(const bf16x8*)(p1);
                bf16x8 c1 = *(const bf16x8*)(p1 + 8);
                bf16x8 c2 = *(const bf16x8*)(p1 + 16);
                bf16x8 c3 = *(const bf16x8*)(p1 + 24);
#pragma unroll
                for (int k = 0; k < 8; k++) {
                    acc[k]      += bf2f(a0[k]) + bf2f(c0[k]);
                    acc[k + 8]  += bf2f(a1[k]) + bf2f(c1[k]);
                    acc[k + 16] += bf2f(a2[k]) + bf2f(c2[k]);
                    acc[k + 24] += bf2f(a3[k]) + bf2f(c3[k]);
                }
            }
            for (; j < m; j++) {
                const short* p0 = &r[((long)bk[j] << 7) + ln * 32];
#pragma unroll
                for (int q = 0; q < 4; q++) {
                    bf16x8 v = *(const bf16x8*)(p0 + q * 8);
#pragma unroll
                    for (int k = 0; k < 8; k++) acc[q * 8 + k] += bf2f(v[k]);
                }
            }
        }
        int nl = tid >> 2;
#pragma unroll
        for (int q = 0; q < 4; q++) {
            bf16x8 s;
#pragma unroll
            for (int k = 0; k < 8; k++) s[k] = f2bf(acc[q * 8 + k]);
            *(bf16x8*)&As[nl][ln * 32 + q * 8] = s;
        }
    }
    __syncthreads();

    // ---- gemm phase: 4 waves, wave handles 64 cols (wn = wave*64) ----
    int lane = tid & 63, wave = tid >> 6;
    int wn = wave * 64;
    int l16 = lane & 15, quad = lane >> 4;

    f32x4 acc[4][4];
#pragma unroll
    for (int i = 0; i < 4; i++)
#pragma unroll
        for (int j = 0; j < 4; j++) acc[i][j] = {0.f, 0.f, 0.f, 0.f};

    for (int k0 = 0; k0 < HIDC; k0 += 64) {
        // stage Bs: 256x64 bf16 slab of w2b (8 bf16x8/thread)
#pragma unroll
        for (int w = 0; w < 8; w++) {
            int f = tid + w * 256;
            int rr = f >> 3, c8 = f & 7;
            *(bf16x8*)&Bs[rr][c8 * 8] =
                *(const bf16x8*)&w2b[(long)rr * HIDC + k0 + c8 * 8];
        }
        __syncthreads();
#pragma unroll
        for (int kk = 0; kk < 64; kk += 32) {
            bf16x8 af[4], bfr[4];
#pragma unroll
            for (int i = 0; i < 4; i++)
                af[i] = *(const bf16x8*)&As[i * 16 + l16][k0 + kk + quad * 8];
#pragma unroll
            for (int j = 0; j < 4; j++)
                bfr[j] = *(const bf16x8*)&Bs[wn + j * 16 + l16][kk + quad * 8];
#pragma unroll
            for (int i = 0; i < 4; i++)
#pragma unroll
                for (int j = 0; j < 4; j++)
                    acc[i][j] = __builtin_amdgcn_mfma_f32_16x16x32_bf16(
                        af[i], bfr[j], acc[i][j], 0, 0, 0);
        }
        __syncthreads();
    }

#pragma unroll
    for (int i = 0; i < 4; i++)
#pragma unroll
        for (int rr = 0; rr < 4; rr++) {
            int grow = node0 + i * 16 + quad * 4 + rr;
            if (grow < NN)
#pragma unroll
                for (int j = 0; j < 4; j++) {
                    int gcol = wn + j * 16 + l16;
                    out[(long)grow * OUTC + gcol] = acc[i][j][rr] + b2[gcol];
                }
        }
}

// ---------------------------------------------------------------------------
// Overflow fixups (expected n==0; exactness preserved by full recompute).
__global__ __launch_bounds__(128) void ovfix1_k(
    const short* __restrict__ h, const float* __restrict__ b1,
    const unsigned short* __restrict__ bucket, const int* __restrict__ cnt,
    const int* __restrict__ ovcnt, const int* __restrict__ ovlist,
    short* __restrict__ r)
{
    int n = *ovcnt; if (n > OV_CAP) n = OV_CAP;
    int c = threadIdx.x;
    for (int i = 0; i < n; i++) {
        int dst = ovlist[i * 2 + 1];
        bool dup = false;
        for (int i2 = 0; i2 < i; i2++)
            if (ovlist[i2 * 2 + 1] == dst) { dup = true; break; }
        if (dup) continue;
        int m = cnt[dst]; if (m > CAP) m = CAP;
        const unsigned short* bk = bucket + (long)dst * CAP;
        float acc = 0.f;
        for (int j = 0; j < m; j++)
            acc += bf2f(h[(long)bk[j] * HIDC + c]);
        for (int i2 = 0; i2 < n; i2++)
            if (ovlist[i2 * 2 + 1] == dst)
                acc += bf2f(h[(long)ovlist[i2 * 2] * HIDC + c]);
        r[(long)dst * HIDC + c] = f2bf(fmaxf(acc + b1[c], 0.f));
    }
}

__global__ __launch_bounds__(256) void ovfix2_k(
    const short* __restrict__ r, const unsigned short* __restrict__ bucket,
    const int* __restrict__ cnt, const int* __restrict__ ovcnt,
    const int* __restrict__ ovlist, const short* __restrict__ w2b,
    const float* __restrict__ b2, float* __restrict__ out)
{
    __shared__ float row[HIDC];
    int n = *ovcnt; if (n > OV_CAP) n = OV_CAP;
    int t = threadIdx.x;
    for (int i = 0; i < n; i++) {
        int dst = ovlist[i * 2 + 1];
        bool dup = false;
        for (int i2 = 0; i2 < i; i2++)
            if (ovlist[i2 * 2 + 1] == dst) { dup = true; break; }
        if (dup) continue;
        if (t < HIDC) {
            int m = cnt[dst]; if (m > CAP) m = CAP;
            const unsigned short* bk = bucket + (long)dst * CAP;
            float acc = 0.f;
            for (int j = 0; j < m; j++)
                acc += bf2f(r[(long)bk[j] * HIDC + t]);
            for (int i2 = 0; i2 < n; i2++)
                if (ovlist[i2 * 2 + 1] == dst)
                    acc += bf2f(r[(long)ovlist[i2 * 2] * HIDC + t]);
            row[t] = bf2f(f2bf(acc));     // match MFMA's bf16 A operand
        }
        __syncthreads();
        float o = 0.f;
        for (int c = 0; c < HIDC; c++)
            o = fmaf(row[c], bf2f(w2b[(long)t * HIDC + c]), o);
        out[(long)dst * OUTC + t] = o + b2[t];
        __syncthreads();
    }
}

extern "C" void kernel_launch(void* const* d_in, const int* in_sizes, int n_in,
                              void* d_out, int out_size, void* d_ws, size_t ws_size,
                              hipStream_t stream) {
    const float* x  = (const float*)d_in[0];
    const int*   ei = (const int*)d_in[1];
    const float* w1 = (const float*)d_in[2];
    const float* b1 = (const float*)d_in[3];
    const float* w2 = (const float*)d_in[4];
    const float* b2 = (const float*)d_in[5];
    float* out = (float*)d_out;

    char* ws = (char*)d_ws;
    size_t off = 0;
    short* h    = (short*)(ws + off); off += (size_t)NN * HIDC * 2;          // 12.8 MB
    short* r    = (short*)(ws + off); off += (size_t)NN * HIDC * 2;          // 12.8 MB
    short* w1b  = (short*)(ws + off); off += (size_t)HIDC * INC * 2;         // 128 KB
    short* w2b  = (short*)(ws + off); off += (size_t)OUTC * HIDC * 2;        // 64 KB
    unsigned short* bucket = (unsigned short*)(ws + off);
    off += (size_t)NN * CAP * 2;                                             // 6.4 MB
    int* cnt    = (int*)(ws + off);   off += (size_t)NN * 4;                 // 0.2 MB
    int* ovcnt  = (int*)(ws + off);   off += 256;
    int* ovlist = (int*)(ws + off);   off += (size_t)OV_CAP * 2 * 4;         // 0.5 MB

    hipMemsetAsync(cnt, 0, (size_t)NN * 4 + 4, stream);    // cnt + ovcnt

    dim3 blk(256);

    // w1,w2 -> bf16
    cvt_w<<<dim3(96), blk, 0, stream>>>(w1, w2, w1b, w2b);

    // build (4 edges/thread, all blocks) || h = bf16(x @ w1b^T)
    fat_build_gemm1<<<dim3(GB1), blk, 0, stream>>>(
        ei, cnt, bucket, ovcnt, ovlist, x, w1b, h);

    // r = bf16(relu(A*h + b1))
    gather1_k<<<dim3((NN + 15) / 16), blk, 0, stream>>>(h, bucket, cnt, b1, r);
    ovfix1_k<<<dim3(1), dim3(128), 0, stream>>>(h, b1, bucket, cnt, ovcnt, ovlist, r);

    // out = (A*r) @ w2b^T + b2   (fused gather+gemm)
    gg2_k<<<dim3(GB1), blk, 0, stream>>>(r, bucket, cnt, w2b, b2, out);
    ovfix2_k<<<dim3(1), blk, 0, stream>>>(r, bucket, cnt, ovcnt, ovlist, w2b, b2, out);
}